// Round 21
// baseline (264.645 us; speedup 1.0000x reference)
//
#include <hip/hip_runtime.h>
#include <hip/hip_bf16.h>
#include <cstdint>
#include <cstddef>

#define N_TOK   8192
#define D_MODEL 1024
#define D_FFN   4096
#define K_TOP   512
#define NHALF   2048   // FFN half-width (fallback path)

typedef __bf16 bf16_t;
typedef __bf16 bf16x8 __attribute__((ext_vector_type(8)));
typedef __bf16 bf16x4 __attribute__((ext_vector_type(4)));
typedef float  f32x4  __attribute__((ext_vector_type(4)));

// ---------------- aux kernels ----------------

// f32 -> bf16, 8 elems/thread
__global__ void cvt_f32_bf16(const float* __restrict__ in, bf16_t* __restrict__ out, int n8) {
  int i = blockIdx.x * blockDim.x + threadIdx.x;
  if (i < n8) {
    const f32x4 v0 = ((const f32x4*)in)[i * 2];
    const f32x4 v1 = ((const f32x4*)in)[i * 2 + 1];
    bf16x8 o;
    o[0] = (bf16_t)v0[0]; o[1] = (bf16_t)v0[1]; o[2] = (bf16_t)v0[2]; o[3] = (bf16_t)v0[3];
    o[4] = (bf16_t)v1[0]; o[5] = (bf16_t)v1[1]; o[6] = (bf16_t)v1[2]; o[7] = (bf16_t)v1[3];
    ((bf16x8*)out)[i] = o;
  }
}

// out[i] += part[i], f32x4 vectorized (deterministic split-K reduction)
__global__ void add_inplace_f32(float* __restrict__ out, const float* __restrict__ part, int n4) {
  int i = blockIdx.x * blockDim.x + threadIdx.x;
  if (i < n4) {
    f32x4 a = ((const f32x4*)out)[i];
    const f32x4 b = ((const f32x4*)part)[i];
    a[0] += b[0]; a[1] += b[1]; a[2] += b[2]; a[3] += b[3];
    ((f32x4*)out)[i] = a;
  }
}

// in: [rows][cols] f32  ->  out: [cols][rows] bf16
__global__ void transpose_cvt(const float* __restrict__ in, bf16_t* __restrict__ out,
                              int rows, int cols) {
  __shared__ float tile[32][33];
  const int tx = threadIdx.x, ty = threadIdx.y;
  const int x = blockIdx.x * 32 + tx;
#pragma unroll
  for (int i = 0; i < 32; i += 8) {
    int y = blockIdx.y * 32 + ty + i;
    tile[ty + i][tx] = in[(size_t)y * cols + x];
  }
  __syncthreads();
  const int xo = blockIdx.y * 32 + tx;
#pragma unroll
  for (int i = 0; i < 32; i += 8) {
    int yo = blockIdx.x * 32 + ty + i;
    out[(size_t)yo * rows + xo] = (bf16_t)tile[tx][ty + i];
  }
}

// dual transpose: wg and wu share tile coordinates
__global__ void transpose_cvt2(const float* __restrict__ in0, const float* __restrict__ in1,
                               bf16_t* __restrict__ out0, bf16_t* __restrict__ out1,
                               int rows, int cols) {
  __shared__ float tile[32][33];
  const int tx = threadIdx.x, ty = threadIdx.y;
  const int x = blockIdx.x * 32 + tx;
  const int xo = blockIdx.y * 32 + tx;
#pragma unroll
  for (int s = 0; s < 2; ++s) {
    const float* in = s ? in1 : in0;
    bf16_t* out = s ? out1 : out0;
    if (s) __syncthreads();
#pragma unroll
    for (int i = 0; i < 32; i += 8) {
      int y = blockIdx.y * 32 + ty + i;
      tile[ty + i][tx] = in[(size_t)y * cols + x];
    }
    __syncthreads();
#pragma unroll
    for (int i = 0; i < 32; i += 8) {
      int yo = blockIdx.x * 32 + ty + i;
      out[(size_t)yo * rows + xo] = (bf16_t)tile[tx][ty + i];
    }
  }
}

// multiplicity counts, packed 8 x 4-bit nibbles per u32, per-row LDS histogram
#define ROWS_PER_BLK 4
__global__ __launch_bounds__(256) void count_scatter_lds(
    const int* __restrict__ idx, unsigned int* __restrict__ M) {
  __shared__ unsigned int loc[ROWS_PER_BLK * (D_FFN / 8)];   // 8 KB
  const int t = threadIdx.x;
  const int r0 = blockIdx.x * ROWS_PER_BLK;

#pragma unroll
  for (int i = 0; i < ROWS_PER_BLK * (D_FFN / 8) / 256; ++i)
    loc[t + i * 256] = 0;
  __syncthreads();

  const int* ip = idx + (size_t)r0 * K_TOP;
#pragma unroll
  for (int i = 0; i < ROWS_PER_BLK * K_TOP / 256; ++i) {
    const int e = t + i * 256;
    const int lr = e >> 9;
    const int j = ip[e];
    atomicAdd(&loc[lr * (D_FFN / 8) + (j >> 3)], 1u << ((j & 7) * 4));
  }
  __syncthreads();

  unsigned int* op = M + (size_t)r0 * (D_FFN / 8);
#pragma unroll
  for (int i = 0; i < ROWS_PER_BLK * (D_FFN / 8) / 256; ++i)
    op[t + i * 256] = loc[t + i * 256];
}

// ---------------- GEMM common ----------------

__device__ __forceinline__ void gload_lds16(const void* g, void* l) {
#if __has_builtin(__builtin_amdgcn_global_load_lds)
  __builtin_amdgcn_global_load_lds((__attribute__((address_space(1))) void*)(g),
                                   (__attribute__((address_space(3))) void*)(l), 16, 0, 0);
#else
  *(bf16x8*)l = *(const bf16x8*)g;
#endif
}

#define MFMA16(ACC, AF, BF)                                                      \
  _Pragma("unroll")                                                              \
  for (int m = 0; m < 4; ++m)                                                    \
    _Pragma("unroll")                                                            \
    for (int n = 0; n < 4; ++n)                                                  \
      ACC[m][n] = __builtin_amdgcn_mfma_f32_16x16x32_bf16(AF[m], BF[n], ACC[m][n], 0, 0, 0);

// SESSION NOTES (locked):
//  - down constraint at full width: grid 256 = 1 block/CU. Fix = split-K=2 with
//    down_3b (72KB x2 = 144KB <= 160KB residency product CHECKED; VGPR 120x4
//    waves = 480 <= 512 ok). Separate C_part + deterministic add (no atomics;
//    R17: 16.8M atomics cost ~30us).
//  - 32x32x16 MFMA: bank-audited dead (32-lane column groups -> 4-way conflict
//    in every LDS geometry that fits 160KB).
//  - Within-probe A/B only; MFMA operands from LDS only (R13).

// ---------------- GEMM1: gate+up fused, tri-buffer BK=32 pipeline ----------
#define BM1 256
#define BN1 128
#define BK1 32
#define NT1 (D_MODEL / BK1)   // 32 K-tiles
#define GU_BUF 32768          // A 16K | Bg 8K | Bu 8K

__global__ __launch_bounds__(512, 2) void gemm_gateup_3b(
    const bf16_t* __restrict__ A,
    const bf16_t* __restrict__ Bg,
    const bf16_t* __restrict__ Bu,
    const unsigned int* __restrict__ cnt,
    bf16_t* __restrict__ Z,          // [N_TOK][zstride]
    int n_base, int zstride)
{
  extern __shared__ char smem[];
  const int t = threadIdx.x;
  const int lane = t & 63;
  const int w = t >> 6;
  const int wr = w >> 1;
  const int wc = w & 1;
  const int l15 = lane & 15;
  const int grp = lane >> 4;
  const int m0 = blockIdx.x * BM1;
  const int n0 = blockIdx.y * BN1;

  const int sA0 = t, sA1 = t + 512;
  const int rA0 = sA0 >> 2, uA0 = (sA0 & 3) ^ ((rA0 >> 1) & 3);
  const int rA1 = sA1 >> 2, uA1 = (sA1 & 3) ^ ((rA1 >> 1) & 3);
  const int rB  = t >> 2,   uB  = (t & 3) ^ ((rB >> 1) & 3);
  const int gA0 = (m0 + rA0) * D_MODEL + uA0 * 8;
  const int gA1 = (m0 + rA1) * D_MODEL + uA1 * 8;
  const int gB  = (n_base + n0 + rB) * D_MODEL + uB * 8;
  const int dA0 = sA0 * 16, dA1 = sA1 * 16, dB = t * 16;

#define GU_STAGE(ti) do {                                                        \
    char* _b = smem + ((ti) % 3) * GU_BUF; const int _k = (ti) * BK1;            \
    gload_lds16(A  + gA0 + _k, _b + dA0);                                        \
    gload_lds16(A  + gA1 + _k, _b + dA1);                                        \
    gload_lds16(Bg + gB  + _k, _b + 16384 + dB);                                 \
    gload_lds16(Bu + gB  + _k, _b + 24576 + dB); } while (0)

  int a_off[4], bg_off[4];
#pragma unroll
  for (int m = 0; m < 4; ++m) {
    const int row = wr * 64 + m * 16 + l15;
    a_off[m] = row * 64 + ((grp ^ ((row >> 1) & 3)) * 16);
  }
#pragma unroll
  for (int n = 0; n < 4; ++n) {
    const int row = wc * 64 + n * 16 + l15;
    bg_off[n] = 16384 + row * 64 + ((grp ^ ((row >> 1) & 3)) * 16);
  }

  GU_STAGE(0); GU_STAGE(1);
  asm volatile("s_waitcnt vmcnt(4)" ::: "memory");
  __builtin_amdgcn_s_barrier();

  bf16x8 af[4], bgf[4], buf_[4];
#pragma unroll
  for (int m = 0; m < 4; ++m) af[m] = *(const bf16x8*)(smem + a_off[m]);
#pragma unroll
  for (int n = 0; n < 4; ++n) bgf[n] = *(const bf16x8*)(smem + bg_off[n]);

  f32x4 accg[4][4] = {};
  f32x4 accu[4][4] = {};

  for (int tt = 0; tt < NT1; ++tt) {
    char* rbuf = smem + (tt % 3) * GU_BUF;
    if (tt + 2 < NT1) GU_STAGE(tt + 2);
#pragma unroll
    for (int n = 0; n < 4; ++n) buf_[n] = *(const bf16x8*)(rbuf + bg_off[n] + 8192);
    asm volatile("s_waitcnt lgkmcnt(4)" ::: "memory");
    __builtin_amdgcn_s_setprio(1);
    MFMA16(accg, af, bgf);
    __builtin_amdgcn_s_setprio(0);
    asm volatile("s_waitcnt lgkmcnt(0)" ::: "memory");
    if (tt + 2 < NT1) { asm volatile("s_waitcnt vmcnt(4)" ::: "memory"); }
    else              { asm volatile("s_waitcnt vmcnt(0)" ::: "memory"); }
    __builtin_amdgcn_s_barrier();
    char* nbuf = smem + ((tt + 1) % 3) * GU_BUF;
    if (tt + 1 < NT1) {
#pragma unroll
      for (int n = 0; n < 4; ++n) bgf[n] = *(const bf16x8*)(nbuf + bg_off[n]);
    }
    __builtin_amdgcn_s_setprio(1);
    MFMA16(accu, af, buf_);
    __builtin_amdgcn_s_setprio(0);
    if (tt + 1 < NT1) {
#pragma unroll
      for (int m = 0; m < 4; ++m) af[m] = *(const bf16x8*)(nbuf + a_off[m]);
    }
  }

#pragma unroll
  for (int m = 0; m < 4; ++m) {
#pragma unroll
    for (int n = 0; n < 4; ++n) {
      const int colL = n0 + wc * 64 + n * 16 + l15;
      const int jg = n_base + colL;
#pragma unroll
      for (int j = 0; j < 4; ++j) {
        const int row = m0 + wr * 64 + m * 16 + grp * 4 + j;
        float g = accg[m][n][j];
        float u = accu[m][n][j];
        unsigned int cw = cnt[(size_t)row * (D_FFN / 8) + (jg >> 3)];
        float c = (float)((cw >> ((jg & 7) * 4)) & 15u);
        float z = c * u * (g / (1.0f + __expf(-g)));
        Z[(size_t)row * zstride + colL] = (bf16_t)z;
      }
    }
  }
#undef GU_STAGE
}

// ---------------- GEMM2: down, tri-buffer BK=32 BM=256, optional split-K ----
// gridDim.z==2 (full path): z=0 -> Cpart, z=1 -> C, each K=ntk*BK2, plain
// stores; deterministic add kernel combines. gridDim.z==1 (half path): C with
// accum flag (Cpart unused).
#define BM2 256
#define BN2 128
#define BK2 32
#define DN_BUF 24576          // A 16K | B 8K  (x3 = 72KB -> 2 blocks/CU fits)

__global__ __launch_bounds__(512, 2) void gemm_down_3b(
    const bf16_t* __restrict__ A,    // Z [N_TOK][zstride]
    const bf16_t* __restrict__ B,    // [D_MODEL][D_FFN]
    float* __restrict__ C,
    float* __restrict__ Cpart,
    int k_base, int accum, int zstride, int ntk)
{
  extern __shared__ char smem[];
  const int t = threadIdx.x;
  const int lane = t & 63;
  const int w = t >> 6;
  const int wr = w >> 1;
  const int wc = w & 1;
  const int l15 = lane & 15;
  const int grp = lane >> 4;
  const int m0 = blockIdx.x * BM2;
  const int n0 = blockIdx.y * BN2;
  const int kz = blockIdx.z * ntk * BK2;   // split-K offset within Z's K

  const int sA0 = t, sA1 = t + 512;
  const int rA0 = sA0 >> 2, uA0 = (sA0 & 3) ^ ((rA0 >> 1) & 3);
  const int rA1 = sA1 >> 2, uA1 = (sA1 & 3) ^ ((rA1 >> 1) & 3);
  const int rB  = t >> 2,   uB  = (t & 3) ^ ((rB >> 1) & 3);
  const int gA0 = (m0 + rA0) * zstride + kz + uA0 * 8;
  const int gA1 = (m0 + rA1) * zstride + kz + uA1 * 8;
  const int gB  = (n0 + rB) * D_FFN + k_base + kz + uB * 8;
  const int dA0 = sA0 * 16, dA1 = sA1 * 16, dB = t * 16;

#define DN_STAGE(ti) do {                                                        \
    char* _b = smem + ((ti) % 3) * DN_BUF; const int _k = (ti) * BK2;            \
    gload_lds16(A + gA0 + _k, _b + dA0);                                         \
    gload_lds16(A + gA1 + _k, _b + dA1);                                         \
    gload_lds16(B + gB  + _k, _b + 16384 + dB); } while (0)

  int a_off[4], b_off[4];
#pragma unroll
  for (int m = 0; m < 4; ++m) {
    const int row = wr * 64 + m * 16 + l15;
    a_off[m] = row * 64 + ((grp ^ ((row >> 1) & 3)) * 16);
  }
#pragma unroll
  for (int n = 0; n < 4; ++n) {
    const int row = wc * 64 + n * 16 + l15;
    b_off[n] = 16384 + row * 64 + ((grp ^ ((row >> 1) & 3)) * 16);
  }

  DN_STAGE(0); DN_STAGE(1);
  asm volatile("s_waitcnt vmcnt(3)" ::: "memory");
  __builtin_amdgcn_s_barrier();

  bf16x8 af[4], bf[4];
#pragma unroll
  for (int m = 0; m < 4; ++m) af[m] = *(const bf16x8*)(smem + a_off[m]);
#pragma unroll
  for (int n = 0; n < 4; ++n) bf[n] = *(const bf16x8*)(smem + b_off[n]);

  f32x4 acc[4][4] = {};

  for (int tt = 0; tt < ntk; ++tt) {
    if (tt + 2 < ntk) DN_STAGE(tt + 2);
    __builtin_amdgcn_s_setprio(1);
    MFMA16(acc, af, bf);
    __builtin_amdgcn_s_setprio(0);
    asm volatile("s_waitcnt lgkmcnt(0)" ::: "memory");
    if (tt + 2 < ntk) { asm volatile("s_waitcnt vmcnt(3)" ::: "memory"); }
    else              { asm volatile("s_waitcnt vmcnt(0)" ::: "memory"); }
    __builtin_amdgcn_s_barrier();
    if (tt + 1 < ntk) {
      char* nbuf = smem + ((tt + 1) % 3) * DN_BUF;
#pragma unroll
      for (int m = 0; m < 4; ++m) af[m] = *(const bf16x8*)(nbuf + a_off[m]);
#pragma unroll
      for (int n = 0; n < 4; ++n) bf[n] = *(const bf16x8*)(nbuf + b_off[n]);
    }
  }

  // epilogue: split mode -> plain store to per-z buffer; else accum-into-C
  float* dst = (gridDim.z == 2 && blockIdx.z == 0) ? Cpart : C;
  const bool doAccum = (gridDim.z == 1) && accum;
#pragma unroll
  for (int m = 0; m < 4; ++m) {
#pragma unroll
    for (int n = 0; n < 4; ++n) {
      const int col = n0 + wc * 64 + n * 16 + l15;
#pragma unroll
      for (int j = 0; j < 4; ++j) {
        const int row = m0 + wr * 64 + m * 16 + grp * 4 + j;
        const size_t off = (size_t)row * D_MODEL + col;
        float prev = doAccum ? dst[off] : 0.0f;
        dst[off] = prev + acc[m][n][j];
      }
    }
  }
#undef DN_STAGE
}

// ---------------- launch ----------------

extern "C" void kernel_launch(void* const* d_in, const int* in_sizes, int n_in,
                              void* d_out, int out_size, void* d_ws, size_t ws_size,
                              hipStream_t stream) {
  const float* x  = (const float*)d_in[0];
  const int*   idx = (const int*)d_in[1];
  const float* wg = (const float*)d_in[2];
  const float* wu = (const float*)d_in[3];
  const float* wd = (const float*)d_in[4];
  float* out = (float*)d_out;

  char* ws = (char*)d_ws;
  const size_t SZ_XB  = (size_t)N_TOK * D_MODEL * 2;   // 16 MB
  const size_t SZ_CNT = (size_t)N_TOK * D_FFN / 2;     // 16 MB
  const size_t SZ_W   = (size_t)D_MODEL * D_FFN * 2;   //  8 MB each
  const size_t SZ_ZF  = (size_t)N_TOK * D_FFN * 2;     // 64 MB (full path)
  // layout: xb | cnt | wgT | wuT | wdT | Z   (xb+cnt adjacent = 32MB dead
  // after gateup -> reused as C_part by full-path split-K down)
  bf16_t* xb  = (bf16_t*)(ws);
  unsigned int* cnt = (unsigned int*)(ws + SZ_XB);
  bf16_t* wgT = (bf16_t*)(ws + SZ_XB + SZ_CNT);
  bf16_t* wuT = (bf16_t*)(ws + SZ_XB + SZ_CNT + SZ_W);
  bf16_t* wdT = (bf16_t*)(ws + SZ_XB + SZ_CNT + 2 * SZ_W);
  bf16_t* Z   = (bf16_t*)(ws + SZ_XB + SZ_CNT + 3 * SZ_W);
  float* Cpart = (float*)(ws);                         // 32 MB over xb+cnt
  const size_t WS_FULL = SZ_XB + SZ_CNT + 3 * SZ_W + SZ_ZF;  // 120 MB (fits, R15)
  const bool full = (ws_size >= WS_FULL);

  (void)hipFuncSetAttribute((const void*)gemm_gateup_3b,
                            hipFuncAttributeMaxDynamicSharedMemorySize, 3 * GU_BUF);
  (void)hipFuncSetAttribute((const void*)gemm_down_3b,
                            hipFuncAttributeMaxDynamicSharedMemorySize, 3 * DN_BUF);

  count_scatter_lds<<<N_TOK / ROWS_PER_BLK, 256, 0, stream>>>(idx, cnt);
  cvt_f32_bf16<<<(N_TOK * D_MODEL / 8 + 255) / 256, 256, 0, stream>>>(x, xb, N_TOK * D_MODEL / 8);
  transpose_cvt2<<<dim3(D_FFN / 32, D_MODEL / 32), dim3(32, 8), 0, stream>>>(
      wg, wu, wgT, wuT, D_MODEL, D_FFN);
  transpose_cvt<<<dim3(D_MODEL / 32, D_FFN / 32), dim3(32, 8), 0, stream>>>(wd, wdT, D_FFN, D_MODEL);

  if (full) {
    gemm_gateup_3b<<<dim3(N_TOK / BM1, D_FFN / BN1), 512, 3 * GU_BUF, stream>>>(
        xb, wgT, wuT, cnt, Z, 0, D_FFN);
    // split-K=2: 512 blocks, 72KB/block -> 2 resident/CU; z=0 -> Cpart, z=1 -> out
    gemm_down_3b<<<dim3(N_TOK / BM2, D_MODEL / BN2, 2), 512, 3 * DN_BUF, stream>>>(
        Z, wdT, out, Cpart, 0, 0, D_FFN, (D_FFN / 2) / BK2);
    add_inplace_f32<<<(N_TOK * D_MODEL / 4 + 255) / 256, 256, 0, stream>>>(
        out, Cpart, N_TOK * D_MODEL / 4);
  } else {
    // half path: xb/cnt stay live across both halves -> NO split (Cpart unused)
    gemm_gateup_3b<<<dim3(N_TOK / BM1, NHALF / BN1), 512, 3 * GU_BUF, stream>>>(
        xb, wgT, wuT, cnt, Z, 0, NHALF);
    gemm_down_3b<<<dim3(N_TOK / BM2, D_MODEL / BN2, 1), 512, 3 * DN_BUF, stream>>>(
        Z, wdT, out, nullptr, 0, 0, NHALF, NHALF / BK2);
    gemm_gateup_3b<<<dim3(N_TOK / BM1, NHALF / BN1), 512, 3 * GU_BUF, stream>>>(
        xb, wgT, wuT, cnt, Z, NHALF, NHALF);
    gemm_down_3b<<<dim3(N_TOK / BM2, D_MODEL / BN2, 1), 512, 3 * DN_BUF, stream>>>(
        Z, wdT, out, nullptr, 0, 1, NHALF, NHALF / BK2);
  }
}

// Round 22
// 254.087 us; speedup vs baseline: 1.0416x; 1.0416x over previous
//
#include <hip/hip_runtime.h>
#include <hip/hip_bf16.h>
#include <cstdint>
#include <cstddef>

#define N_TOK   8192
#define D_MODEL 1024
#define D_FFN   4096
#define K_TOP   512
#define NHALF   2048   // FFN half-width (fallback path)

typedef __bf16 bf16_t;
typedef __bf16 bf16x8 __attribute__((ext_vector_type(8)));
typedef __bf16 bf16x4 __attribute__((ext_vector_type(4)));
typedef float  f32x4  __attribute__((ext_vector_type(4)));

// ---------------- aux kernels ----------------

// f32 -> bf16, 8 elems/thread (two 16B reads, one 16B store = coalescing sweet spot)
__global__ void cvt_f32_bf16(const float* __restrict__ in, bf16_t* __restrict__ out, int n8) {
  int i = blockIdx.x * blockDim.x + threadIdx.x;
  if (i < n8) {
    const f32x4 v0 = ((const f32x4*)in)[i * 2];
    const f32x4 v1 = ((const f32x4*)in)[i * 2 + 1];
    bf16x8 o;
    o[0] = (bf16_t)v0[0]; o[1] = (bf16_t)v0[1]; o[2] = (bf16_t)v0[2]; o[3] = (bf16_t)v0[3];
    o[4] = (bf16_t)v1[0]; o[5] = (bf16_t)v1[1]; o[6] = (bf16_t)v1[2]; o[7] = (bf16_t)v1[3];
    ((bf16x8*)out)[i] = o;
  }
}

// in: [rows][cols] f32  ->  out: [cols][rows] bf16   (B^T layout for GEMM)
__global__ void transpose_cvt(const float* __restrict__ in, bf16_t* __restrict__ out,
                              int rows, int cols) {
  __shared__ float tile[32][33];
  const int tx = threadIdx.x, ty = threadIdx.y;
  const int x = blockIdx.x * 32 + tx;
#pragma unroll
  for (int i = 0; i < 32; i += 8) {
    int y = blockIdx.y * 32 + ty + i;
    tile[ty + i][tx] = in[(size_t)y * cols + x];
  }
  __syncthreads();
  const int xo = blockIdx.y * 32 + tx;
#pragma unroll
  for (int i = 0; i < 32; i += 8) {
    int yo = blockIdx.x * 32 + ty + i;
    out[(size_t)yo * rows + xo] = (bf16_t)tile[tx][ty + i];
  }
}

// dual transpose: wg and wu share tile coordinates (one launch, shared addr calc)
__global__ void transpose_cvt2(const float* __restrict__ in0, const float* __restrict__ in1,
                               bf16_t* __restrict__ out0, bf16_t* __restrict__ out1,
                               int rows, int cols) {
  __shared__ float tile[32][33];
  const int tx = threadIdx.x, ty = threadIdx.y;
  const int x = blockIdx.x * 32 + tx;
  const int xo = blockIdx.y * 32 + tx;
#pragma unroll
  for (int s = 0; s < 2; ++s) {
    const float* in = s ? in1 : in0;
    bf16_t* out = s ? out1 : out0;
    if (s) __syncthreads();   // all reads of tile (s=0) done before overwrite
#pragma unroll
    for (int i = 0; i < 32; i += 8) {
      int y = blockIdx.y * 32 + ty + i;
      tile[ty + i][tx] = in[(size_t)y * cols + x];
    }
    __syncthreads();
#pragma unroll
    for (int i = 0; i < 32; i += 8) {
      int yo = blockIdx.x * 32 + ty + i;
      out[(size_t)yo * rows + xo] = (bf16_t)tile[tx][ty + i];
    }
  }
}

// multiplicity counts, packed 8 x 4-bit nibbles per u32, per-row LDS histogram
#define ROWS_PER_BLK 4
__global__ __launch_bounds__(256) void count_scatter_lds(
    const int* __restrict__ idx, unsigned int* __restrict__ M) {
  __shared__ unsigned int loc[ROWS_PER_BLK * (D_FFN / 8)];   // 8 KB
  const int t = threadIdx.x;
  const int r0 = blockIdx.x * ROWS_PER_BLK;

#pragma unroll
  for (int i = 0; i < ROWS_PER_BLK * (D_FFN / 8) / 256; ++i)
    loc[t + i * 256] = 0;
  __syncthreads();

  const int* ip = idx + (size_t)r0 * K_TOP;
#pragma unroll
  for (int i = 0; i < ROWS_PER_BLK * K_TOP / 256; ++i) {
    const int e = t + i * 256;
    const int lr = e >> 9;
    const int j = ip[e];
    atomicAdd(&loc[lr * (D_FFN / 8) + (j >> 3)], 1u << ((j & 7) * 4));
  }
  __syncthreads();

  unsigned int* op = M + (size_t)r0 * (D_FFN / 8);
#pragma unroll
  for (int i = 0; i < ROWS_PER_BLK * (D_FFN / 8) / 256; ++i)
    op[t + i * 256] = loc[t + i * 256];
}

// ---------------- GEMM common ----------------

__device__ __forceinline__ void gload_lds16(const void* g, void* l) {
#if __has_builtin(__builtin_amdgcn_global_load_lds)
  __builtin_amdgcn_global_load_lds((__attribute__((address_space(1))) void*)(g),
                                   (__attribute__((address_space(3))) void*)(l), 16, 0, 0);
#else
  *(bf16x8*)l = *(const bf16x8*)g;
#endif
}

// 16 MFMA: ACC[m][n] += AF[m] * BF[n]
#define MFMA16(ACC, AF, BF)                                                      \
  _Pragma("unroll")                                                              \
  for (int m = 0; m < 4; ++m)                                                    \
    _Pragma("unroll")                                                            \
    for (int n = 0; n < 4; ++n)                                                  \
      ACC[m][n] = __builtin_amdgcn_mfma_f32_16x16x32_bf16(AF[m], BF[n], ACC[m][n], 0, 0, 0);

// SESSION FINAL (R21): best-measured configuration = R20, 254.5us.
//  - Masked-dense reformulation: Z = mult(i,j)*silu(G)*U, dense bf16 GEMMs.
//  - gateup 138us (MfmaUtil 45%, conflicts 0): register-capped 2 waves/SIMD
//    (dual acc 128 AGPR), LDS-traffic-bound; 6 schedule variants bracket it.
//  - down 90us: grid 256 = 1 block/CU; ALL alternatives measured worse
//    (split-K-atomic 132, split-K-buffered ~100, BM128 104, 3b==8p).
//  - aux 23us: BW-bound.
//  Locked lessons: within-probe A/B only; LDS residency product check;
//  MFMA operands from LDS only; never cap launch_bounds below acc floor;
//  swizzle involution on both sides (rule 21).

// ---------------- GEMM1: gate+up fused, tri-buffer BK=32 pipeline ----------
// Swizzle p=u^((r>>1)&3) on 64B rows (conflict-free, R12-verified).
#define BM1 256
#define BN1 128
#define BK1 32
#define NT1 (D_MODEL / BK1)   // 32 K-tiles
#define GU_BUF 32768          // bytes per buffer: A 16K | Bg 8K | Bu 8K

__global__ __launch_bounds__(512, 2) void gemm_gateup_3b(
    const bf16_t* __restrict__ A,    // [N_TOK][D_MODEL]
    const bf16_t* __restrict__ Bg,   // [D_FFN][D_MODEL]
    const bf16_t* __restrict__ Bu,   // [D_FFN][D_MODEL]
    const unsigned int* __restrict__ cnt,
    bf16_t* __restrict__ Z,          // [N_TOK][zstride]
    int n_base, int zstride)
{
  extern __shared__ char smem[];
  const int t = threadIdx.x;
  const int lane = t & 63;
  const int w = t >> 6;
  const int wr = w >> 1;           // 0..3 (M)
  const int wc = w & 1;            // 0..1 (N)
  const int l15 = lane & 15;
  const int grp = lane >> 4;       // 0..3
  const int m0 = blockIdx.x * BM1;
  const int n0 = blockIdx.y * BN1;

  // ---- staging maps (inverse-swizzled global src, linear LDS dest) ----
  const int sA0 = t, sA1 = t + 512;              // A slots 0..1023 (256r x 4u)
  const int rA0 = sA0 >> 2, uA0 = (sA0 & 3) ^ ((rA0 >> 1) & 3);
  const int rA1 = sA1 >> 2, uA1 = (sA1 & 3) ^ ((rA1 >> 1) & 3);
  const int rB  = t >> 2,   uB  = (t & 3) ^ ((rB >> 1) & 3);  // B slots 0..511
  const int gA0 = (m0 + rA0) * D_MODEL + uA0 * 8;
  const int gA1 = (m0 + rA1) * D_MODEL + uA1 * 8;
  const int gB  = (n_base + n0 + rB) * D_MODEL + uB * 8;
  const int dA0 = sA0 * 16, dA1 = sA1 * 16, dB = t * 16;

#define GU_STAGE(ti) do {                                                        \
    char* _b = smem + ((ti) % 3) * GU_BUF; const int _k = (ti) * BK1;            \
    gload_lds16(A  + gA0 + _k, _b + dA0);                                        \
    gload_lds16(A  + gA1 + _k, _b + dA1);                                        \
    gload_lds16(Bg + gB  + _k, _b + 16384 + dB);                                 \
    gload_lds16(Bu + gB  + _k, _b + 24576 + dB); } while (0)

  // ---- ds_read byte offsets (swizzled) ----
  int a_off[4], bg_off[4];
#pragma unroll
  for (int m = 0; m < 4; ++m) {
    const int row = wr * 64 + m * 16 + l15;
    a_off[m] = row * 64 + ((grp ^ ((row >> 1) & 3)) * 16);
  }
#pragma unroll
  for (int n = 0; n < 4; ++n) {
    const int row = wc * 64 + n * 16 + l15;
    bg_off[n] = 16384 + row * 64 + ((grp ^ ((row >> 1) & 3)) * 16);
  }

  // ---- prologue: buffers 0,1 in flight; wait 0; preload af/bg(0) ----
  GU_STAGE(0); GU_STAGE(1);
  asm volatile("s_waitcnt vmcnt(4)" ::: "memory");   // buf0 done, buf1 flying
  __builtin_amdgcn_s_barrier();

  bf16x8 af[4], bgf[4], buf_[4];
#pragma unroll
  for (int m = 0; m < 4; ++m) af[m] = *(const bf16x8*)(smem + a_off[m]);
#pragma unroll
  for (int n = 0; n < 4; ++n) bgf[n] = *(const bf16x8*)(smem + bg_off[n]);

  f32x4 accg[4][4] = {};
  f32x4 accu[4][4] = {};

  for (int tt = 0; tt < NT1; ++tt) {
    char* rbuf = smem + (tt % 3) * GU_BUF;
    if (tt + 2 < NT1) GU_STAGE(tt + 2);
    // bu(t) reads fly under MFMA-G
#pragma unroll
    for (int n = 0; n < 4; ++n) buf_[n] = *(const bf16x8*)(rbuf + bg_off[n] + 8192);
    asm volatile("s_waitcnt lgkmcnt(4)" ::: "memory");  // af/bg(t) drained (restage safety)
    __builtin_amdgcn_s_setprio(1);
    MFMA16(accg, af, bgf);
    __builtin_amdgcn_s_setprio(0);
    asm volatile("s_waitcnt lgkmcnt(0)" ::: "memory");  // bu(t) drained
    if (tt + 2 < NT1) { asm volatile("s_waitcnt vmcnt(4)" ::: "memory"); }  // buf[t+1] ready
    else              { asm volatile("s_waitcnt vmcnt(0)" ::: "memory"); }
    __builtin_amdgcn_s_barrier();                       // single barrier per K-tile
    char* nbuf = smem + ((tt + 1) % 3) * GU_BUF;
    if (tt + 1 < NT1) {
#pragma unroll
      for (int n = 0; n < 4; ++n) bgf[n] = *(const bf16x8*)(nbuf + bg_off[n]);
    }
    __builtin_amdgcn_s_setprio(1);
    MFMA16(accu, af, buf_);                             // af/bg(t+1) reads fly under this
    __builtin_amdgcn_s_setprio(0);
    if (tt + 1 < NT1) {
#pragma unroll
      for (int m = 0; m < 4; ++m) af[m] = *(const bf16x8*)(nbuf + a_off[m]);
    }
  }

  // ---- epilogue: Z = cnt * u * silu(g) ----
#pragma unroll
  for (int m = 0; m < 4; ++m) {
#pragma unroll
    for (int n = 0; n < 4; ++n) {
      const int colL = n0 + wc * 64 + n * 16 + l15;
      const int jg = n_base + colL;
#pragma unroll
      for (int j = 0; j < 4; ++j) {
        const int row = m0 + wr * 64 + m * 16 + grp * 4 + j;
        float g = accg[m][n][j];
        float u = accu[m][n][j];
        unsigned int cw = cnt[(size_t)row * (D_FFN / 8) + (jg >> 3)];
        float c = (float)((cw >> ((jg & 7) * 4)) & 15u);
        float z = c * u * (g / (1.0f + __expf(-g)));
        Z[(size_t)row * zstride + colL] = (bf16_t)z;
      }
    }
  }
#undef GU_STAGE
}

// ---------------- GEMM2: down, tri-buffer BK=32 BM=256 ------
#define BM2 256
#define BN2 128
#define BK2 32
#define DN_BUF 24576          // A 16K | B 8K

__global__ __launch_bounds__(512, 2) void gemm_down_3b(
    const bf16_t* __restrict__ A,    // Z [N_TOK][zstride]
    const bf16_t* __restrict__ B,    // [D_MODEL][D_FFN]  (w_down^T)
    float* __restrict__ C,           // [N_TOK][D_MODEL]
    int k_base, int accum, int zstride, int ntk)
{
  extern __shared__ char smem[];
  const int t = threadIdx.x;
  const int lane = t & 63;
  const int w = t >> 6;
  const int wr = w >> 1;
  const int wc = w & 1;
  const int l15 = lane & 15;
  const int grp = lane >> 4;
  const int m0 = blockIdx.x * BM2;
  const int n0 = blockIdx.y * BN2;

  const int sA0 = t, sA1 = t + 512;
  const int rA0 = sA0 >> 2, uA0 = (sA0 & 3) ^ ((rA0 >> 1) & 3);
  const int rA1 = sA1 >> 2, uA1 = (sA1 & 3) ^ ((rA1 >> 1) & 3);
  const int rB  = t >> 2,   uB  = (t & 3) ^ ((rB >> 1) & 3);
  const int gA0 = (m0 + rA0) * zstride + uA0 * 8;
  const int gA1 = (m0 + rA1) * zstride + uA1 * 8;
  const int gB  = (n0 + rB) * D_FFN + k_base + uB * 8;
  const int dA0 = sA0 * 16, dA1 = sA1 * 16, dB = t * 16;

#define DN_STAGE(ti) do {                                                        \
    char* _b = smem + ((ti) % 3) * DN_BUF; const int _k = (ti) * BK2;            \
    gload_lds16(A + gA0 + _k, _b + dA0);                                         \
    gload_lds16(A + gA1 + _k, _b + dA1);                                         \
    gload_lds16(B + gB  + _k, _b + 16384 + dB); } while (0)

  int a_off[4], b_off[4];
#pragma unroll
  for (int m = 0; m < 4; ++m) {
    const int row = wr * 64 + m * 16 + l15;
    a_off[m] = row * 64 + ((grp ^ ((row >> 1) & 3)) * 16);
  }
#pragma unroll
  for (int n = 0; n < 4; ++n) {
    const int row = wc * 64 + n * 16 + l15;
    b_off[n] = 16384 + row * 64 + ((grp ^ ((row >> 1) & 3)) * 16);
  }

  DN_STAGE(0); DN_STAGE(1);
  asm volatile("s_waitcnt vmcnt(3)" ::: "memory");   // buf0 done, buf1 flying
  __builtin_amdgcn_s_barrier();

  bf16x8 af[4], bf[4];
#pragma unroll
  for (int m = 0; m < 4; ++m) af[m] = *(const bf16x8*)(smem + a_off[m]);
#pragma unroll
  for (int n = 0; n < 4; ++n) bf[n] = *(const bf16x8*)(smem + b_off[n]);

  f32x4 acc[4][4] = {};

  for (int tt = 0; tt < ntk; ++tt) {
    if (tt + 2 < ntk) DN_STAGE(tt + 2);
    __builtin_amdgcn_s_setprio(1);
    MFMA16(acc, af, bf);                               // compiler waits af/bf deps
    __builtin_amdgcn_s_setprio(0);
    asm volatile("s_waitcnt lgkmcnt(0)" ::: "memory"); // af/bf(t) drained (restage safety)
    if (tt + 2 < ntk) { asm volatile("s_waitcnt vmcnt(3)" ::: "memory"); }  // buf[t+1] ready
    else              { asm volatile("s_waitcnt vmcnt(0)" ::: "memory"); }
    __builtin_amdgcn_s_barrier();
    if (tt + 1 < ntk) {
      char* nbuf = smem + ((tt + 1) % 3) * DN_BUF;
#pragma unroll
      for (int m = 0; m < 4; ++m) af[m] = *(const bf16x8*)(nbuf + a_off[m]);
#pragma unroll
      for (int n = 0; n < 4; ++n) bf[n] = *(const bf16x8*)(nbuf + b_off[n]);
    }
  }

  // epilogue (C/D map verified)
#pragma unroll
  for (int m = 0; m < 4; ++m) {
#pragma unroll
    for (int n = 0; n < 4; ++n) {
      const int col = n0 + wc * 64 + n * 16 + l15;
#pragma unroll
      for (int j = 0; j < 4; ++j) {
        const int row = m0 + wr * 64 + m * 16 + grp * 4 + j;
        const size_t off = (size_t)row * D_MODEL + col;
        float prev = accum ? C[off] : 0.0f;
        C[off] = prev + acc[m][n][j];
      }
    }
  }
#undef DN_STAGE
}

// ---------------- launch ----------------

extern "C" void kernel_launch(void* const* d_in, const int* in_sizes, int n_in,
                              void* d_out, int out_size, void* d_ws, size_t ws_size,
                              hipStream_t stream) {
  const float* x  = (const float*)d_in[0];
  const int*   idx = (const int*)d_in[1];
  const float* wg = (const float*)d_in[2];
  const float* wu = (const float*)d_in[3];
  const float* wd = (const float*)d_in[4];
  float* out = (float*)d_out;

  char* ws = (char*)d_ws;
  const size_t SZ_XB  = (size_t)N_TOK * D_MODEL * 2;   // 16 MB
  const size_t SZ_W   = (size_t)D_MODEL * D_FFN * 2;   //  8 MB each
  const size_t SZ_CNT = (size_t)N_TOK * D_FFN / 2;     // 16 MB
  const size_t SZ_ZF  = (size_t)N_TOK * D_FFN * 2;     // 64 MB (full path)
  bf16_t* xb  = (bf16_t*)(ws);
  bf16_t* wgT = (bf16_t*)(ws + SZ_XB);
  bf16_t* wuT = (bf16_t*)(ws + SZ_XB + SZ_W);
  bf16_t* wdT = (bf16_t*)(ws + SZ_XB + 2 * SZ_W);
  unsigned int* cnt = (unsigned int*)(ws + SZ_XB + 3 * SZ_W);
  bf16_t* Z   = (bf16_t*)(ws + SZ_XB + 3 * SZ_W + SZ_CNT);
  const size_t WS_FULL = SZ_XB + 3 * SZ_W + SZ_CNT + SZ_ZF;  // 120 MB (fits, R15)
  const bool full = (ws_size >= WS_FULL);

  (void)hipFuncSetAttribute((const void*)gemm_gateup_3b,
                            hipFuncAttributeMaxDynamicSharedMemorySize, 3 * GU_BUF);
  (void)hipFuncSetAttribute((const void*)gemm_down_3b,
                            hipFuncAttributeMaxDynamicSharedMemorySize, 3 * DN_BUF);

  count_scatter_lds<<<N_TOK / ROWS_PER_BLK, 256, 0, stream>>>(idx, cnt);
  cvt_f32_bf16<<<(N_TOK * D_MODEL / 8 + 255) / 256, 256, 0, stream>>>(x, xb, N_TOK * D_MODEL / 8);
  transpose_cvt2<<<dim3(D_FFN / 32, D_MODEL / 32), dim3(32, 8), 0, stream>>>(
      wg, wu, wgT, wuT, D_MODEL, D_FFN);
  transpose_cvt<<<dim3(D_MODEL / 32, D_FFN / 32), dim3(32, 8), 0, stream>>>(wd, wdT, D_FFN, D_MODEL);

  if (full) {
    // full-width Z: one gateup (all 4096 cols), one down (K=4096, C written once)
    gemm_gateup_3b<<<dim3(N_TOK / BM1, D_FFN / BN1), 512, 3 * GU_BUF, stream>>>(
        xb, wgT, wuT, cnt, Z, 0, D_FFN);
    gemm_down_3b<<<dim3(N_TOK / BM2, D_MODEL / BN2), 512, 3 * DN_BUF, stream>>>(
        Z, wdT, out, 0, 0, D_FFN, D_FFN / BK2);
  } else {
    // half path: two FFN halves, Z buffer reused
    gemm_gateup_3b<<<dim3(N_TOK / BM1, NHALF / BN1), 512, 3 * GU_BUF, stream>>>(
        xb, wgT, wuT, cnt, Z, 0, NHALF);
    gemm_down_3b<<<dim3(N_TOK / BM2, D_MODEL / BN2), 512, 3 * DN_BUF, stream>>>(
        Z, wdT, out, 0, 0, NHALF, NHALF / BK2);
    gemm_gateup_3b<<<dim3(N_TOK / BM1, NHALF / BN1), 512, 3 * GU_BUF, stream>>>(
        xb, wgT, wuT, cnt, Z, NHALF, NHALF);
    gemm_down_3b<<<dim3(N_TOK / BM2, D_MODEL / BN2), 512, 3 * DN_BUF, stream>>>(
        Z, wdT, out, NHALF, 1, NHALF, NHALF / BK2);
  }
}